// Round 1
// baseline (1855.366 us; speedup 1.0000x reference)
//
#include <hip/hip_runtime.h>

#define N_PTS   100000
#define M_CL    12500
#define E0_N    1600000
#define E1_N    400000

// ============================ CSR build ============================

__global__ __launch_bounds__(256) void k_count(const int* __restrict__ edges, int E, int* __restrict__ cnt){
  int e = blockIdx.x*256 + threadIdx.x;
  if (e < E) atomicAdd(&cnt[edges[2*e+1]], 1);
}

// chunk = 2048 elements per block
__global__ __launch_bounds__(256) void k_chunk_sum(const int* __restrict__ cnt, int n, int* __restrict__ part){
  __shared__ int sd[256];
  int t = threadIdx.x, base = blockIdx.x*2048;
  int s = 0;
  #pragma unroll
  for (int r=0;r<8;++r){ int i = base + t*8 + r; if (i<n) s += cnt[i]; }
  sd[t]=s; __syncthreads();
  for (int st=128; st>0; st>>=1){ if (t<st) sd[t]+=sd[t+st]; __syncthreads(); }
  if (t==0) part[blockIdx.x]=sd[0];
}

__global__ void k_scan_part(int* part, int B, int* offs, int n){
  if (threadIdx.x==0 && blockIdx.x==0){
    int acc=0;
    for (int i=0;i<B;++i){ int v=part[i]; part[i]=acc; acc+=v; }
    offs[n]=acc;
  }
}

__global__ __launch_bounds__(256) void k_chunk_scan(const int* __restrict__ cnt, int n,
                                                    const int* __restrict__ part, int* __restrict__ offs){
  __shared__ int sd[256];
  int t=threadIdx.x, base=blockIdx.x*2048;
  int v[8]; int s=0;
  #pragma unroll
  for (int r=0;r<8;++r){ int i=base+t*8+r; v[r] = (i<n)?cnt[i]:0; s+=v[r]; }
  sd[t]=s; __syncthreads();
  for (int st=1; st<256; st<<=1){
    int x = (t>=st)? sd[t-st] : 0;
    __syncthreads();
    sd[t]+=x;
    __syncthreads();
  }
  int acc = part[blockIdx.x] + sd[t] - s;   // exclusive base for this thread
  #pragma unroll
  for (int r=0;r<8;++r){ int i=base+t*8+r; if (i<n) offs[i]=acc; acc+=v[r]; }
}

__global__ __launch_bounds__(256) void k_fill(const int* __restrict__ edges, int E,
                                              const int* __restrict__ offs, int* __restrict__ cur,
                                              int* __restrict__ csr){
  int e = blockIdx.x*256+threadIdx.x;
  if (e<E){
    int d = edges[2*e+1], s = edges[2*e];
    int p = atomicAdd(&cur[d],1);
    csr[offs[d]+p] = s;
  }
}

// ============================ feature encoder (f1 + rel) ============================

__global__ __launch_bounds__(256) void k_f1(const float* __restrict__ features, const float* __restrict__ points,
                                            const float* __restrict__ centers, const int* __restrict__ labels,
                                            const float* __restrict__ W, const float* __restrict__ b,
                                            float* __restrict__ rel, float* __restrict__ f1, int n){
  int lane = threadIdx.x & 63;
  int gw = (blockIdx.x*256 + threadIdx.x) >> 6;
  int nw = (gridDim.x*256) >> 6;
  float Wf0=W[0*64+lane], Wf1=W[1*64+lane], Wf2=W[2*64+lane], Wf3=W[3*64+lane];
  float wr0=W[4*64+lane], wr1=W[5*64+lane], wr2=W[6*64+lane];
  float bias=b[lane];
  for (int i=gw; i<n; i+=nw){
    int lb = labels[i];
    float rx = points[i*3+0]-centers[lb*3+0];
    float ry = points[i*3+1]-centers[lb*3+1];
    float rz = points[i*3+2]-centers[lb*3+2];
    if (lane==0){ rel[i*3+0]=rx; rel[i*3+1]=ry; rel[i*3+2]=rz; }
    float acc = bias + wr0*rx + wr1*ry + wr2*rz;
    acc += features[i*4+0]*Wf0 + features[i*4+1]*Wf1;
    acc += features[i*4+2]*Wf2 + features[i*4+3]*Wf3;
    f1[(size_t)i*64+lane] = fmaxf(acc, 0.f);
  }
}

// ============================ node MLP (64->64, wave per row) ============================
// out[i][:] = act(A[gather?][:] @ W[0:64] (+ rel[i]@W[64:67]) + b) (+ r1) (+ r2)

template<bool RELU, bool USE_REL, int NRES, bool GATHER>
__global__ __launch_bounds__(256) void k_mlp(const float* __restrict__ A, const int* __restrict__ gidx,
                                             const float* __restrict__ rel,
                                             const float* __restrict__ W, const float* __restrict__ b,
                                             const float* __restrict__ r1, const float* __restrict__ r2,
                                             float* __restrict__ out, int n){
  int lane = threadIdx.x & 63;
  int gw = (blockIdx.x*256 + threadIdx.x) >> 6;
  int nw = (gridDim.x*256) >> 6;
  float Wc[64];
  #pragma unroll
  for (int k=0;k<64;++k) Wc[k] = W[k*64+lane];
  float wr0=0.f, wr1=0.f, wr2=0.f;
  if (USE_REL){ wr0=W[64*64+lane]; wr1=W[65*64+lane]; wr2=W[66*64+lane]; }
  float bias = b[lane];
  for (int i=gw; i<n; i+=nw){
    int ar = GATHER ? gidx[i] : i;
    const float4* Arow = (const float4*)(A + (size_t)ar*64);
    float a0=0.f,a1=0.f,a2=0.f,a3=0.f;
    #pragma unroll
    for (int kk=0; kk<16; ++kk){
      float4 a4 = Arow[kk];
      a0 += a4.x*Wc[4*kk+0];
      a1 += a4.y*Wc[4*kk+1];
      a2 += a4.z*Wc[4*kk+2];
      a3 += a4.w*Wc[4*kk+3];
    }
    float acc = bias + (a0+a1) + (a2+a3);
    if (USE_REL) acc += rel[i*3+0]*wr0 + rel[i*3+1]*wr1 + rel[i*3+2]*wr2;
    if (RELU) acc = fmaxf(acc, 0.f);
    if (NRES>=1) acc += r1[(size_t)i*64+lane];
    if (NRES>=2) acc += r2[(size_t)i*64+lane];
    out[(size_t)i*64+lane] = acc;
  }
}

// ============================ edge aggregation (segment max via CSR) ============================
// agg[d][j] = max(0, max_{s in in(d)} ( g[s][j] + Wp[:,j] . (pos[s]-pos[d]) ))
// (g already contains +be; relu folded into the 0 init)

__global__ __launch_bounds__(256) void k_edge_agg(const int* __restrict__ offs, const int* __restrict__ csr,
                                                  const float* __restrict__ pos, const float* __restrict__ g,
                                                  const float* __restrict__ Wp, float* __restrict__ agg, int n){
  int lane = threadIdx.x & 63;
  int gw = (blockIdx.x*256 + threadIdx.x) >> 6;
  int nw = (gridDim.x*256) >> 6;
  float w0 = Wp[0*64+lane], w1 = Wp[1*64+lane], w2 = Wp[2*64+lane];
  for (int i=gw; i<n; i+=nw){
    int b = offs[i], e = offs[i+1];
    float px = pos[i*3+0], py = pos[i*3+1], pz = pos[i*3+2];
    float m = 0.f;
    for (int k=b; k<e; ++k){
      int s = csr[k];
      float dx = pos[s*3+0]-px;
      float dy = pos[s*3+1]-py;
      float dz = pos[s*3+2]-pz;
      float v = g[(size_t)s*64+lane] + w0*dx + w1*dy + w2*dz;
      m = fmaxf(m, v);
    }
    agg[(size_t)i*64+lane] = m;
  }
}

// ============================ segment sum (cluster pooling) ============================

__global__ __launch_bounds__(256) void k_seg_sum(const float* __restrict__ h, const int* __restrict__ labels,
                                                 float* __restrict__ c, int n){
  int idx = blockIdx.x*256 + threadIdx.x;
  if (idx >= n*64) return;
  int i = idx >> 6, j = idx & 63;
  __hip_atomic_fetch_add(&c[labels[i]*64+j], h[idx], __ATOMIC_RELAXED, __HIP_MEMORY_SCOPE_AGENT);
}

// ============================ classifier: out = (f61 + f2) @ Wc + bc ============================

__global__ __launch_bounds__(256) void k_out(const float* __restrict__ f61, const float* __restrict__ f2,
                                             const float* __restrict__ Wc, const float* __restrict__ bc,
                                             float* __restrict__ out, int n){
  int idx = blockIdx.x*256 + threadIdx.x;
  if (idx >= n*8) return;
  int i = idx >> 3, j = idx & 7;
  float a0=0.f,a1=0.f,a2=0.f,a3=0.f;
  #pragma unroll
  for (int k=0;k<64;k+=4){
    a0 += (f61[(size_t)i*64+k+0]+f2[(size_t)i*64+k+0])*Wc[(k+0)*8+j];
    a1 += (f61[(size_t)i*64+k+1]+f2[(size_t)i*64+k+1])*Wc[(k+1)*8+j];
    a2 += (f61[(size_t)i*64+k+2]+f2[(size_t)i*64+k+2])*Wc[(k+2)*8+j];
    a3 += (f61[(size_t)i*64+k+3]+f2[(size_t)i*64+k+3])*Wc[(k+3)*8+j];
  }
  out[idx] = bc[j] + (a0+a1) + (a2+a3);
}

// ============================ host launcher ============================

extern "C" void kernel_launch(void* const* d_in, const int* in_sizes, int n_in,
                              void* d_out, int out_size, void* d_ws, size_t ws_size,
                              hipStream_t stream){
  const float* features = (const float*)d_in[0];
  const float* points   = (const float*)d_in[1];
  const float* centers  = (const float*)d_in[2];
  const int*   l0e      = (const int*)d_in[3];
  const int*   l1e      = (const int*)d_in[4];
  const int*   labels   = (const int*)d_in[5];
  const float* W_fe = (const float*)d_in[6];
  const float* b_fe = (const float*)d_in[7];
  const float* mWe  = (const float*)d_in[8];   // (4,67,64)
  const float* mbe  = (const float*)d_in[9];   // (4,64)
  const float* mWu  = (const float*)d_in[10];  // (4,64,64)
  const float* mbu  = (const float*)d_in[11];  // (4,64)
  const float* W_m1 = (const float*)d_in[12];
  const float* b_m1 = (const float*)d_in[13];
  const float* W_m2 = (const float*)d_in[14];
  const float* b_m2 = (const float*)d_in[15];
  const float* gWe  = (const float*)d_in[16];  // (2,67,64)
  const float* gbe  = (const float*)d_in[17];
  const float* gWu  = (const float*)d_in[18];
  const float* gbu  = (const float*)d_in[19];
  const float* W_l  = (const float*)d_in[20];
  const float* b_l  = (const float*)d_in[21];
  const float* W_c  = (const float*)d_in[22];
  const float* b_c  = (const float*)d_in[23];
  float* out = (float*)d_out;

  // ---- workspace carve-up (everything rewritten each call; ws is poisoned) ----
  char* w = (char*)d_ws;
  size_t off = 0;
  auto alloc = [&](size_t bytes)->void*{
    void* p = (void*)(w + off);
    off = (off + bytes + 255) & ~(size_t)255;
    return p;
  };
  float* rel  = (float*)alloc((size_t)N_PTS*3*4);
  float* buf0 = (float*)alloc((size_t)N_PTS*64*4);  // f1 -> h -> f5 -> f6_1
  float* buf1 = (float*)alloc((size_t)N_PTS*64*4);  // f2 (persists)
  float* buf2 = (float*)alloc((size_t)N_PTS*64*4);  // f2_1 -> f6
  float* gbuf = (float*)alloc((size_t)N_PTS*64*4);  // per-layer g
  float* abuf = (float*)alloc((size_t)N_PTS*64*4);  // per-layer agg
  float* cbuf = (float*)alloc((size_t)M_CL*64*4);   // segment_sum target
  float* f3   = (float*)alloc((size_t)M_CL*64*4);
  float* cg   = (float*)alloc((size_t)M_CL*64*4);
  float* cagg = (float*)alloc((size_t)M_CL*64*4);
  float* f4   = (float*)alloc((size_t)M_CL*64*4);
  float* f41  = (float*)alloc((size_t)M_CL*64*4);
  int* cnt0  = (int*)alloc((size_t)N_PTS*4);
  int* offs0 = (int*)alloc((size_t)(N_PTS+1)*4);
  int* cur0  = (int*)alloc((size_t)N_PTS*4);
  int* csr0  = (int*)alloc((size_t)E0_N*4);
  int* cnt1  = (int*)alloc((size_t)M_CL*4);
  int* offs1 = (int*)alloc((size_t)(M_CL+1)*4);
  int* cur1  = (int*)alloc((size_t)M_CL*4);
  int* csr1  = (int*)alloc((size_t)E1_N*4);
  int* part0 = (int*)alloc(64*4);
  int* part1 = (int*)alloc(64*4);
  (void)ws_size; (void)in_sizes; (void)n_in; (void)out_size;

  const int B0 = (N_PTS + 2047)/2048;   // 49
  const int B1 = (M_CL  + 2047)/2048;   // 7
  const int GB_N = 2048;                             // grid-stride blocks for N-sized wave kernels
  const int GB_M = (M_CL + 3)/4 > 2048 ? 2048 : (M_CL + 3)/4;

  // ---- zero the atomically-built buffers ----
  hipMemsetAsync(cnt0, 0, (size_t)N_PTS*4, stream);
  hipMemsetAsync(cur0, 0, (size_t)N_PTS*4, stream);
  hipMemsetAsync(cnt1, 0, (size_t)M_CL*4, stream);
  hipMemsetAsync(cur1, 0, (size_t)M_CL*4, stream);
  hipMemsetAsync(cbuf, 0, (size_t)M_CL*64*4, stream);

  // ---- CSR for l0 (used by 4 layers) and l1 (used by 2) ----
  k_count<<<(E0_N+255)/256, 256, 0, stream>>>(l0e, E0_N, cnt0);
  k_chunk_sum<<<B0, 256, 0, stream>>>(cnt0, N_PTS, part0);
  k_scan_part<<<1, 64, 0, stream>>>(part0, B0, offs0, N_PTS);
  k_chunk_scan<<<B0, 256, 0, stream>>>(cnt0, N_PTS, part0, offs0);
  k_fill<<<(E0_N+255)/256, 256, 0, stream>>>(l0e, E0_N, offs0, cur0, csr0);

  k_count<<<(E1_N+255)/256, 256, 0, stream>>>(l1e, E1_N, cnt1);
  k_chunk_sum<<<B1, 256, 0, stream>>>(cnt1, M_CL, part1);
  k_scan_part<<<1, 64, 0, stream>>>(part1, B1, offs1, M_CL);
  k_chunk_scan<<<B1, 256, 0, stream>>>(cnt1, M_CL, part1, offs1);
  k_fill<<<(E1_N+255)/256, 256, 0, stream>>>(l1e, E1_N, offs1, cur1, csr1);

  // ---- encoder: rel + f1 ----
  k_f1<<<GB_N, 256, 0, stream>>>(features, points, centers, labels, W_fe, b_fe, rel, buf0, N_PTS);

  // ---- mini layer 0: f2 = L(f1) ----
  k_mlp<false,false,0,false><<<GB_N,256,0,stream>>>(buf0, nullptr, nullptr, mWe+0*4288+192, mbe+0*64, nullptr, nullptr, gbuf, N_PTS);
  k_edge_agg<<<GB_N,256,0,stream>>>(offs0, csr0, points, gbuf, mWe+0*4288, abuf, N_PTS);
  k_mlp<true ,false,1,false><<<GB_N,256,0,stream>>>(abuf, nullptr, nullptr, mWu+0*4096, mbu+0*64, buf0, nullptr, buf1, N_PTS);

  // ---- mini layer 1: f2_1 = L(f2) ----
  k_mlp<false,false,0,false><<<GB_N,256,0,stream>>>(buf1, nullptr, nullptr, mWe+1*4288+192, mbe+1*64, nullptr, nullptr, gbuf, N_PTS);
  k_edge_agg<<<GB_N,256,0,stream>>>(offs0, csr0, points, gbuf, mWe+1*4288, abuf, N_PTS);
  k_mlp<true ,false,1,false><<<GB_N,256,0,stream>>>(abuf, nullptr, nullptr, mWu+1*4096, mbu+1*64, buf1, nullptr, buf2, N_PTS);

  // ---- h = relu([f2_1, rel] @ W_m1 + b_m1) ; c = segment_sum(h, labels) ; f3 ----
  k_mlp<true ,true ,0,false><<<GB_N,256,0,stream>>>(buf2, nullptr, rel, W_m1, b_m1, nullptr, nullptr, buf0, N_PTS);
  k_seg_sum<<<(N_PTS*64+255)/256,256,0,stream>>>(buf0, labels, cbuf, N_PTS);
  k_mlp<true ,false,0,false><<<GB_M,256,0,stream>>>(cbuf, nullptr, nullptr, W_m2, b_m2, nullptr, nullptr, f3, M_CL);

  // ---- cluster layer 0: f4 = L(f3) ----
  k_mlp<false,false,0,false><<<GB_M,256,0,stream>>>(f3, nullptr, nullptr, gWe+0*4288+192, gbe+0*64, nullptr, nullptr, cg, M_CL);
  k_edge_agg<<<GB_M,256,0,stream>>>(offs1, csr1, centers, cg, gWe+0*4288, cagg, M_CL);
  k_mlp<true ,false,1,false><<<GB_M,256,0,stream>>>(cagg, nullptr, nullptr, gWu+0*4096, gbu+0*64, f3, nullptr, f4, M_CL);

  // ---- cluster layer 1: f4_1 = L(f4) ----
  k_mlp<false,false,0,false><<<GB_M,256,0,stream>>>(f4, nullptr, nullptr, gWe+1*4288+192, gbe+1*64, nullptr, nullptr, cg, M_CL);
  k_edge_agg<<<GB_M,256,0,stream>>>(offs1, csr1, centers, cg, gWe+1*4288, cagg, M_CL);
  k_mlp<true ,false,1,false><<<GB_M,256,0,stream>>>(cagg, nullptr, nullptr, gWu+1*4096, gbu+1*64, f4, nullptr, f41, M_CL);

  // ---- f5 = relu([f4_1[labels], rel] @ W_l + b_l) ----
  k_mlp<true ,true ,0,true ><<<GB_N,256,0,stream>>>(f41, labels, rel, W_l, b_l, nullptr, nullptr, buf0, N_PTS);

  // ---- mini layer 2: f6 = L(f5) + f2_1  (written over buf2) ----
  k_mlp<false,false,0,false><<<GB_N,256,0,stream>>>(buf0, nullptr, nullptr, mWe+2*4288+192, mbe+2*64, nullptr, nullptr, gbuf, N_PTS);
  k_edge_agg<<<GB_N,256,0,stream>>>(offs0, csr0, points, gbuf, mWe+2*4288, abuf, N_PTS);
  k_mlp<true ,false,2,false><<<GB_N,256,0,stream>>>(abuf, nullptr, nullptr, mWu+2*4096, mbu+2*64, buf0, buf2, buf2, N_PTS);

  // ---- mini layer 3: f6_1 = L(f6) ----
  k_mlp<false,false,0,false><<<GB_N,256,0,stream>>>(buf2, nullptr, nullptr, mWe+3*4288+192, mbe+3*64, nullptr, nullptr, gbuf, N_PTS);
  k_edge_agg<<<GB_N,256,0,stream>>>(offs0, csr0, points, gbuf, mWe+3*4288, abuf, N_PTS);
  k_mlp<true ,false,1,false><<<GB_N,256,0,stream>>>(abuf, nullptr, nullptr, mWu+3*4096, mbu+3*64, buf2, nullptr, buf0, N_PTS);

  // ---- out = (f6_1 + f2) @ W_c + b_c ----
  k_out<<<(N_PTS*8+255)/256,256,0,stream>>>(buf0, buf1, W_c, b_c, out, N_PTS);
}

// Round 2
// 1718.935 us; speedup vs baseline: 1.0794x; 1.0794x over previous
//
#include <hip/hip_runtime.h>

#define N_PTS   100000
#define M_CL    12500
#define E0_N    1600000
#define E1_N    400000

typedef unsigned short ushortT;

__device__ inline ushortT f2bf(float x){
  union{float f; unsigned u;} v; v.f = x;
  unsigned r = v.u + 0x7fffu + ((v.u >> 16) & 1u);   // RNE
  return (ushortT)(r >> 16);
}
__device__ inline float bf2f(ushortT h){
  union{unsigned u; float f;} v; v.u = ((unsigned)h) << 16;
  return v.f;
}

// ============================ CSR build ============================

__global__ __launch_bounds__(256) void k_count(const int* __restrict__ edges, int E, int* __restrict__ cnt){
  int e = blockIdx.x*256 + threadIdx.x;
  if (e < E) atomicAdd(&cnt[edges[2*e+1]], 1);
}

// chunk = 2048 elements per block
__global__ __launch_bounds__(256) void k_chunk_sum(const int* __restrict__ cnt, int n, int* __restrict__ part){
  __shared__ int sd[256];
  int t = threadIdx.x, base = blockIdx.x*2048;
  int s = 0;
  #pragma unroll
  for (int r=0;r<8;++r){ int i = base + t*8 + r; if (i<n) s += cnt[i]; }
  sd[t]=s; __syncthreads();
  for (int st=128; st>0; st>>=1){ if (t<st) sd[t]+=sd[t+st]; __syncthreads(); }
  if (t==0) part[blockIdx.x]=sd[0];
}

// B <= 64: single-wave shuffle scan (replaces serial dependent-load loop)
__global__ void k_scan_part(int* part, int B, int* offs, int n){
  int lane = threadIdx.x & 63;
  int v = (lane < B) ? part[lane] : 0;
  int orig = v;
  #pragma unroll
  for (int st=1; st<64; st<<=1){
    int x = __shfl_up(v, st, 64);
    if (lane >= st) v += x;
  }
  if (lane < B) part[lane] = v - orig;   // exclusive chunk base
  if (lane == 63) offs[n] = v;           // grand total
}

__global__ __launch_bounds__(256) void k_chunk_scan(const int* __restrict__ cnt, int n,
                                                    const int* __restrict__ part, int* __restrict__ offs){
  __shared__ int sd[256];
  int t=threadIdx.x, base=blockIdx.x*2048;
  int v[8]; int s=0;
  #pragma unroll
  for (int r=0;r<8;++r){ int i=base+t*8+r; v[r] = (i<n)?cnt[i]:0; s+=v[r]; }
  sd[t]=s; __syncthreads();
  for (int st=1; st<256; st<<=1){
    int x = (t>=st)? sd[t-st] : 0;
    __syncthreads();
    sd[t]+=x;
    __syncthreads();
  }
  int acc = part[blockIdx.x] + sd[t] - s;   // exclusive base for this thread
  #pragma unroll
  for (int r=0;r<8;++r){ int i=base+t*8+r; if (i<n) offs[i]=acc; acc+=v[r]; }
}

__global__ __launch_bounds__(256) void k_fill(const int* __restrict__ edges, int E,
                                              const int* __restrict__ offs, int* __restrict__ cur,
                                              int* __restrict__ csr){
  int e = blockIdx.x*256+threadIdx.x;
  if (e<E){
    int d = edges[2*e+1], s = edges[2*e];
    int p = atomicAdd(&cur[d],1);
    csr[offs[d]+p] = s;
  }
}

// ============================ feature encoder (f1 + rel) ============================

__global__ __launch_bounds__(256) void k_f1(const float* __restrict__ features, const float* __restrict__ points,
                                            const float* __restrict__ centers, const int* __restrict__ labels,
                                            const float* __restrict__ W, const float* __restrict__ b,
                                            float* __restrict__ rel, float* __restrict__ f1, int n){
  int lane = threadIdx.x & 63;
  int gw = (blockIdx.x*256 + threadIdx.x) >> 6;
  int nw = (gridDim.x*256) >> 6;
  float Wf0=W[0*64+lane], Wf1=W[1*64+lane], Wf2=W[2*64+lane], Wf3=W[3*64+lane];
  float wr0=W[4*64+lane], wr1=W[5*64+lane], wr2=W[6*64+lane];
  float bias=b[lane];
  for (int i=gw; i<n; i+=nw){
    int lb = labels[i];
    float rx = points[i*3+0]-centers[lb*3+0];
    float ry = points[i*3+1]-centers[lb*3+1];
    float rz = points[i*3+2]-centers[lb*3+2];
    if (lane==0){ rel[i*3+0]=rx; rel[i*3+1]=ry; rel[i*3+2]=rz; }
    float acc = bias + wr0*rx + wr1*ry + wr2*rz;
    acc += features[i*4+0]*Wf0 + features[i*4+1]*Wf1;
    acc += features[i*4+2]*Wf2 + features[i*4+3]*Wf3;
    f1[(size_t)i*64+lane] = fmaxf(acc, 0.f);
  }
}

// ============================ node MLP (64->64, wave per row) ============================
// out[i][:] = act(A[gather?][:] @ W[0:64] (+ rel[i]@W[64:67]) + b) (+ r1) (+ r2)
// OUTBF: store bf16 (for edge-message buffers g)

template<bool RELU, bool USE_REL, int NRES, bool GATHER, bool OUTBF>
__global__ __launch_bounds__(256) void k_mlp(const float* __restrict__ A, const int* __restrict__ gidx,
                                             const float* __restrict__ rel,
                                             const float* __restrict__ W, const float* __restrict__ b,
                                             const float* __restrict__ r1, const float* __restrict__ r2,
                                             void* __restrict__ outv, int n){
  int lane = threadIdx.x & 63;
  int gw = (blockIdx.x*256 + threadIdx.x) >> 6;
  int nw = (gridDim.x*256) >> 6;
  float Wc[64];
  #pragma unroll
  for (int k=0;k<64;++k) Wc[k] = W[k*64+lane];
  float wr0=0.f, wr1=0.f, wr2=0.f;
  if (USE_REL){ wr0=W[64*64+lane]; wr1=W[65*64+lane]; wr2=W[66*64+lane]; }
  float bias = b[lane];
  for (int i=gw; i<n; i+=nw){
    int ar = GATHER ? gidx[i] : i;
    const float4* Arow = (const float4*)(A + (size_t)ar*64);
    float a0=0.f,a1=0.f,a2=0.f,a3=0.f;
    #pragma unroll
    for (int kk=0; kk<16; ++kk){
      float4 a4 = Arow[kk];
      a0 += a4.x*Wc[4*kk+0];
      a1 += a4.y*Wc[4*kk+1];
      a2 += a4.z*Wc[4*kk+2];
      a3 += a4.w*Wc[4*kk+3];
    }
    float acc = bias + (a0+a1) + (a2+a3);
    if (USE_REL) acc += rel[i*3+0]*wr0 + rel[i*3+1]*wr1 + rel[i*3+2]*wr2;
    if (RELU) acc = fmaxf(acc, 0.f);
    if (NRES>=1) acc += r1[(size_t)i*64+lane];
    if (NRES>=2) acc += r2[(size_t)i*64+lane];
    if (OUTBF) ((ushortT*)outv)[(size_t)i*64+lane] = f2bf(acc);
    else       ((float*)outv)[(size_t)i*64+lane] = acc;
  }
}

// ============================ edge aggregation (segment max via CSR) ============================
// agg[d][j] = max(0, max_{s in in(d)} ( g[s][j] + Wp[:,j] . (pos[s]-pos[d]) ))
// g in bf16 (halves gather bytes); relu folded into the 0 init; unroll x4 for MLP.

__global__ __launch_bounds__(256) void k_edge_agg(const int* __restrict__ offs, const int* __restrict__ csr,
                                                  const float* __restrict__ pos, const ushortT* __restrict__ g,
                                                  const float* __restrict__ Wp, float* __restrict__ agg, int n){
  int lane = threadIdx.x & 63;
  int gw = (blockIdx.x*256 + threadIdx.x) >> 6;
  int nw = (gridDim.x*256) >> 6;
  float w0 = Wp[0*64+lane], w1 = Wp[1*64+lane], w2 = Wp[2*64+lane];
  for (int i=gw; i<n; i+=nw){
    int b = offs[i], e = offs[i+1];
    float px = pos[i*3+0], py = pos[i*3+1], pz = pos[i*3+2];
    float m0=0.f, m1=0.f, m2=0.f, m3=0.f;
    int k = b;
    for (; k+4<=e; k+=4){
      int s0=csr[k+0], s1=csr[k+1], s2=csr[k+2], s3=csr[k+3];
      const float* p0=pos+3*s0; const float* p1=pos+3*s1;
      const float* p2=pos+3*s2; const float* p3=pos+3*s3;
      float g0=bf2f(g[(size_t)s0*64+lane]);
      float g1=bf2f(g[(size_t)s1*64+lane]);
      float g2=bf2f(g[(size_t)s2*64+lane]);
      float g3=bf2f(g[(size_t)s3*64+lane]);
      m0=fmaxf(m0, g0 + w0*(p0[0]-px) + w1*(p0[1]-py) + w2*(p0[2]-pz));
      m1=fmaxf(m1, g1 + w0*(p1[0]-px) + w1*(p1[1]-py) + w2*(p1[2]-pz));
      m2=fmaxf(m2, g2 + w0*(p2[0]-px) + w1*(p2[1]-py) + w2*(p2[2]-pz));
      m3=fmaxf(m3, g3 + w0*(p3[0]-px) + w1*(p3[1]-py) + w2*(p3[2]-pz));
    }
    for (; k<e; ++k){
      int s=csr[k];
      m0=fmaxf(m0, bf2f(g[(size_t)s*64+lane]) + w0*(pos[3*s]-px) + w1*(pos[3*s+1]-py) + w2*(pos[3*s+2]-pz));
    }
    agg[(size_t)i*64+lane] = fmaxf(fmaxf(m0,m1),fmaxf(m2,m3));
  }
}

// ============================ segment sum (cluster pooling) ============================

__global__ __launch_bounds__(256) void k_seg_sum(const float* __restrict__ h, const int* __restrict__ labels,
                                                 float* __restrict__ c, int n){
  int idx = blockIdx.x*256 + threadIdx.x;
  if (idx >= n*64) return;
  int i = idx >> 6, j = idx & 63;
  __hip_atomic_fetch_add(&c[labels[i]*64+j], h[idx], __ATOMIC_RELAXED, __HIP_MEMORY_SCOPE_AGENT);
}

// ============================ classifier: out = (f61 + f2) @ Wc + bc ============================

__global__ __launch_bounds__(256) void k_out(const float* __restrict__ f61, const float* __restrict__ f2,
                                             const float* __restrict__ Wc, const float* __restrict__ bc,
                                             float* __restrict__ out, int n){
  int idx = blockIdx.x*256 + threadIdx.x;
  if (idx >= n*8) return;
  int i = idx >> 3, j = idx & 7;
  float a0=0.f,a1=0.f,a2=0.f,a3=0.f;
  #pragma unroll
  for (int k=0;k<64;k+=4){
    a0 += (f61[(size_t)i*64+k+0]+f2[(size_t)i*64+k+0])*Wc[(k+0)*8+j];
    a1 += (f61[(size_t)i*64+k+1]+f2[(size_t)i*64+k+1])*Wc[(k+1)*8+j];
    a2 += (f61[(size_t)i*64+k+2]+f2[(size_t)i*64+k+2])*Wc[(k+2)*8+j];
    a3 += (f61[(size_t)i*64+k+3]+f2[(size_t)i*64+k+3])*Wc[(k+3)*8+j];
  }
  out[idx] = bc[j] + (a0+a1) + (a2+a3);
}

// ============================ host launcher ============================

extern "C" void kernel_launch(void* const* d_in, const int* in_sizes, int n_in,
                              void* d_out, int out_size, void* d_ws, size_t ws_size,
                              hipStream_t stream){
  const float* features = (const float*)d_in[0];
  const float* points   = (const float*)d_in[1];
  const float* centers  = (const float*)d_in[2];
  const int*   l0e      = (const int*)d_in[3];
  const int*   l1e      = (const int*)d_in[4];
  const int*   labels   = (const int*)d_in[5];
  const float* W_fe = (const float*)d_in[6];
  const float* b_fe = (const float*)d_in[7];
  const float* mWe  = (const float*)d_in[8];   // (4,67,64)
  const float* mbe  = (const float*)d_in[9];   // (4,64)
  const float* mWu  = (const float*)d_in[10];  // (4,64,64)
  const float* mbu  = (const float*)d_in[11];  // (4,64)
  const float* W_m1 = (const float*)d_in[12];
  const float* b_m1 = (const float*)d_in[13];
  const float* W_m2 = (const float*)d_in[14];
  const float* b_m2 = (const float*)d_in[15];
  const float* gWe  = (const float*)d_in[16];  // (2,67,64)
  const float* gbe  = (const float*)d_in[17];
  const float* gWu  = (const float*)d_in[18];
  const float* gbu  = (const float*)d_in[19];
  const float* W_l  = (const float*)d_in[20];
  const float* b_l  = (const float*)d_in[21];
  const float* W_c  = (const float*)d_in[22];
  const float* b_c  = (const float*)d_in[23];
  float* out = (float*)d_out;

  // ---- workspace carve-up ----
  char* w = (char*)d_ws;
  size_t off = 0;
  auto alloc = [&](size_t bytes)->void*{
    void* p = (void*)(w + off);
    off = (off + bytes + 255) & ~(size_t)255;
    return p;
  };
  float* rel  = (float*)alloc((size_t)N_PTS*3*4);
  float* buf0 = (float*)alloc((size_t)N_PTS*64*4);   // f1 -> h -> f5 -> f6_1
  float* buf1 = (float*)alloc((size_t)N_PTS*64*4);   // f2 (persists)
  float* buf2 = (float*)alloc((size_t)N_PTS*64*4);   // f2_1 -> f6
  ushortT* gbuf = (ushortT*)alloc((size_t)N_PTS*64*2); // per-layer g (bf16)
  float* abuf = (float*)alloc((size_t)N_PTS*64*4);   // per-layer agg
  float* cbuf = (float*)alloc((size_t)M_CL*64*4);    // segment_sum target
  float* f3   = (float*)alloc((size_t)M_CL*64*4);
  ushortT* cg = (ushortT*)alloc((size_t)M_CL*64*2);  // cluster g (bf16)
  float* cagg = (float*)alloc((size_t)M_CL*64*4);
  float* f4   = (float*)alloc((size_t)M_CL*64*4);
  float* f41  = (float*)alloc((size_t)M_CL*64*4);
  // zeroed-counter block (contiguous -> single memset)
  char* zbase = (char*)alloc(0);
  int* cnt0  = (int*)alloc((size_t)N_PTS*4);
  int* cur0  = (int*)alloc((size_t)N_PTS*4);
  int* cnt1  = (int*)alloc((size_t)M_CL*4);
  int* cur1  = (int*)alloc((size_t)M_CL*4);
  size_t zbytes = (size_t)((char*)(w+off) - zbase);
  int* offs0 = (int*)alloc((size_t)(N_PTS+1)*4);
  int* csr0  = (int*)alloc((size_t)E0_N*4);
  int* offs1 = (int*)alloc((size_t)(M_CL+1)*4);
  int* csr1  = (int*)alloc((size_t)E1_N*4);
  int* part0 = (int*)alloc(64*4);
  int* part1 = (int*)alloc(64*4);
  (void)ws_size; (void)in_sizes; (void)n_in; (void)out_size;

  const int B0 = (N_PTS + 2047)/2048;   // 49
  const int B1 = (M_CL  + 2047)/2048;   // 7
  const int GB_N = 2048;
  const int GB_M = 2048;

  hipMemsetAsync(zbase, 0, zbytes, stream);
  hipMemsetAsync(cbuf, 0, (size_t)M_CL*64*4, stream);

  // ---- CSR for l0 (used by 4 layers) and l1 (used by 2) ----
  k_count<<<(E0_N+255)/256, 256, 0, stream>>>(l0e, E0_N, cnt0);
  k_chunk_sum<<<B0, 256, 0, stream>>>(cnt0, N_PTS, part0);
  k_scan_part<<<1, 64, 0, stream>>>(part0, B0, offs0, N_PTS);
  k_chunk_scan<<<B0, 256, 0, stream>>>(cnt0, N_PTS, part0, offs0);
  k_fill<<<(E0_N+255)/256, 256, 0, stream>>>(l0e, E0_N, offs0, cur0, csr0);

  k_count<<<(E1_N+255)/256, 256, 0, stream>>>(l1e, E1_N, cnt1);
  k_chunk_sum<<<B1, 256, 0, stream>>>(cnt1, M_CL, part1);
  k_scan_part<<<1, 64, 0, stream>>>(part1, B1, offs1, M_CL);
  k_chunk_scan<<<B1, 256, 0, stream>>>(cnt1, M_CL, part1, offs1);
  k_fill<<<(E1_N+255)/256, 256, 0, stream>>>(l1e, E1_N, offs1, cur1, csr1);

  // ---- encoder: rel + f1 ----
  k_f1<<<GB_N, 256, 0, stream>>>(features, points, centers, labels, W_fe, b_fe, rel, buf0, N_PTS);

  // ---- mini layer 0: f2 = L(f1) ----
  k_mlp<false,false,0,false,true ><<<GB_N,256,0,stream>>>(buf0, nullptr, nullptr, mWe+0*4288+192, mbe+0*64, nullptr, nullptr, gbuf, N_PTS);
  k_edge_agg<<<GB_N,256,0,stream>>>(offs0, csr0, points, gbuf, mWe+0*4288, abuf, N_PTS);
  k_mlp<true ,false,1,false,false><<<GB_N,256,0,stream>>>(abuf, nullptr, nullptr, mWu+0*4096, mbu+0*64, buf0, nullptr, buf1, N_PTS);

  // ---- mini layer 1: f2_1 = L(f2) ----
  k_mlp<false,false,0,false,true ><<<GB_N,256,0,stream>>>(buf1, nullptr, nullptr, mWe+1*4288+192, mbe+1*64, nullptr, nullptr, gbuf, N_PTS);
  k_edge_agg<<<GB_N,256,0,stream>>>(offs0, csr0, points, gbuf, mWe+1*4288, abuf, N_PTS);
  k_mlp<true ,false,1,false,false><<<GB_N,256,0,stream>>>(abuf, nullptr, nullptr, mWu+1*4096, mbu+1*64, buf1, nullptr, buf2, N_PTS);

  // ---- h = relu([f2_1, rel] @ W_m1 + b_m1) ; c = segment_sum(h, labels) ; f3 ----
  k_mlp<true ,true ,0,false,false><<<GB_N,256,0,stream>>>(buf2, nullptr, rel, W_m1, b_m1, nullptr, nullptr, buf0, N_PTS);
  k_seg_sum<<<(N_PTS*64+255)/256,256,0,stream>>>(buf0, labels, cbuf, N_PTS);
  k_mlp<true ,false,0,false,false><<<GB_M,256,0,stream>>>(cbuf, nullptr, nullptr, W_m2, b_m2, nullptr, nullptr, f3, M_CL);

  // ---- cluster layer 0: f4 = L(f3) ----
  k_mlp<false,false,0,false,true ><<<GB_M,256,0,stream>>>(f3, nullptr, nullptr, gWe+0*4288+192, gbe+0*64, nullptr, nullptr, cg, M_CL);
  k_edge_agg<<<GB_M,256,0,stream>>>(offs1, csr1, centers, cg, gWe+0*4288, cagg, M_CL);
  k_mlp<true ,false,1,false,false><<<GB_M,256,0,stream>>>(cagg, nullptr, nullptr, gWu+0*4096, gbu+0*64, f3, nullptr, f4, M_CL);

  // ---- cluster layer 1: f4_1 = L(f4) ----
  k_mlp<false,false,0,false,true ><<<GB_M,256,0,stream>>>(f4, nullptr, nullptr, gWe+1*4288+192, gbe+1*64, nullptr, nullptr, cg, M_CL);
  k_edge_agg<<<GB_M,256,0,stream>>>(offs1, csr1, centers, cg, gWe+1*4288, cagg, M_CL);
  k_mlp<true ,false,1,false,false><<<GB_M,256,0,stream>>>(cagg, nullptr, nullptr, gWu+1*4096, gbu+1*64, f4, nullptr, f41, M_CL);

  // ---- f5 = relu([f4_1[labels], rel] @ W_l + b_l) ----
  k_mlp<true ,true ,0,true ,false><<<GB_N,256,0,stream>>>(f41, labels, rel, W_l, b_l, nullptr, nullptr, buf0, N_PTS);

  // ---- mini layer 2: f6 = L(f5) + f2_1 ----
  k_mlp<false,false,0,false,true ><<<GB_N,256,0,stream>>>(buf0, nullptr, nullptr, mWe+2*4288+192, mbe+2*64, nullptr, nullptr, gbuf, N_PTS);
  k_edge_agg<<<GB_N,256,0,stream>>>(offs0, csr0, points, gbuf, mWe+2*4288, abuf, N_PTS);
  k_mlp<true ,false,2,false,false><<<GB_N,256,0,stream>>>(abuf, nullptr, nullptr, mWu+2*4096, mbu+2*64, buf0, buf2, buf2, N_PTS);

  // ---- mini layer 3: f6_1 = L(f6) ----
  k_mlp<false,false,0,false,true ><<<GB_N,256,0,stream>>>(buf2, nullptr, nullptr, mWe+3*4288+192, mbe+3*64, nullptr, nullptr, gbuf, N_PTS);
  k_edge_agg<<<GB_N,256,0,stream>>>(offs0, csr0, points, gbuf, mWe+3*4288, abuf, N_PTS);
  k_mlp<true ,false,1,false,false><<<GB_N,256,0,stream>>>(abuf, nullptr, nullptr, mWu+3*4096, mbu+3*64, buf2, nullptr, buf0, N_PTS);

  // ---- out = (f6_1 + f2) @ W_c + b_c ----
  k_out<<<(N_PTS*8+255)/256,256,0,stream>>>(buf0, buf1, W_c, b_c, out, N_PTS);
}

// Round 3
// 1210.870 us; speedup vs baseline: 1.5323x; 1.4196x over previous
//
#include <hip/hip_runtime.h>

#define N_PTS   100000
#define M_CL    12500
#define E0_N    1600000
#define E1_N    400000

#define NB      128          // buckets for CSR build
#define BIN_CAP 48           // LDS staging entries per bucket
#define RANGE0  782          // ceil(N/NB)
#define RANGE1  98           // ceil(M/NB)
#define BCAP0   16384        // tmp region per bucket (l0, mean 12504)
#define BCAP1   4096         // tmp region per bucket (l1, mean 3125)

typedef unsigned short ushortT;

__device__ inline ushortT f2bf(float x){
  union{float f; unsigned u;} v; v.f = x;
  unsigned r = v.u + 0x7fffu + ((v.u >> 16) & 1u);   // RNE
  return (ushortT)(r >> 16);
}
__device__ inline float bf2f(ushortT h){
  union{unsigned u; float f;} v; v.u = ((unsigned)h) << 16;
  return v.f;
}

// ============================ bucketed CSR build ============================

__global__ void k_binit(int* c0, int* c1){
  int t = threadIdx.x;
  if (t < NB) c0[t] = t*BCAP0;
  else        c1[t-NB] = (t-NB)*BCAP1;
}

// Phase A: bin edges by dst range; LDS write-combining; packed (src<<11)|localDst
template<int RANGE>
__global__ __launch_bounds__(256) void k_bin(const int* __restrict__ edges, int E,
                                             int* __restrict__ bcur, unsigned* __restrict__ tmp){
  __shared__ unsigned stage[NB*BIN_CAP];   // 24 KB
  __shared__ int scnt[NB];
  __shared__ int sbase[NB];
  int tid = threadIdx.x;
  int nchunks = (E + 2047) / 2048;
  for (int c = blockIdx.x; c < nchunks; c += gridDim.x){
    int base = c*2048;
    if (tid < NB) scnt[tid] = 0;
    __syncthreads();
    #pragma unroll
    for (int r=0;r<8;++r){
      int e = base + r*256 + tid;
      if (e < E){
        int s = edges[2*e], d = edges[2*e+1];
        int bk = d / RANGE;                       // compile-time divisor
        unsigned packed = ((unsigned)s << 11) | (unsigned)(d - bk*RANGE);
        int pos = atomicAdd(&scnt[bk], 1);
        if (pos < BIN_CAP) stage[bk*BIN_CAP+pos] = packed;
        else tmp[atomicAdd(&bcur[bk],1)] = packed;   // rare overflow fallback
      }
    }
    __syncthreads();
    if (tid < NB){
      int nfl = scnt[tid]; if (nfl > BIN_CAP) nfl = BIN_CAP;
      sbase[tid] = atomicAdd(&bcur[tid], nfl);
    }
    __syncthreads();
    int wv = tid >> 6, ln = tid & 63;
    for (int bb=0; bb<NB/4; ++bb){
      int bk = wv*(NB/4) + bb;
      int nfl = scnt[bk]; if (nfl > BIN_CAP) nfl = BIN_CAP;
      if (ln < nfl) tmp[sbase[bk]+ln] = stage[bk*BIN_CAP+ln];
    }
    __syncthreads();
  }
}

// exclusive scan of the 128 bucket counts (2 blocks: 0->l0, 1->l1)
__global__ void k_scan_bases(const int* c0, int* bb0, int* off0e,
                             const int* c1, int* bb1, int* off1e){
  const int* cur = blockIdx.x ? c1 : c0;
  int* bb = blockIdx.x ? bb1 : bb0;
  int* offe = blockIdx.x ? off1e : off0e;
  int BC = blockIdx.x ? BCAP1 : BCAP0;
  int lane = threadIdx.x & 63;
  int v0 = cur[2*lane]   - (2*lane)*BC;
  int v1 = cur[2*lane+1] - (2*lane+1)*BC;
  int psum = v0 + v1, sc = psum;
  #pragma unroll
  for (int st=1; st<64; st<<=1){
    int x = __shfl_up(sc, st, 64);
    if (lane >= st) sc += x;
  }
  int ex = sc - psum;
  bb[2*lane] = ex; bb[2*lane+1] = ex + v0;
  if (lane == 63) *offe = sc;
}

// Phase B: per-bucket histogram + scan + L2-local scatter -> offs + csr
template<int RANGE, int BCAP>
__global__ __launch_bounds__(256) void k_csr_build(const unsigned* __restrict__ tmp, const int* __restrict__ bcur,
                                                   const int* __restrict__ bb, int n,
                                                   int* __restrict__ offs, int* __restrict__ csr){
  constexpr int K = (RANGE + 255) / 256;
  __shared__ int hist[RANGE];
  __shared__ int part[256];
  int b = blockIdx.x, tid = threadIdx.x;
  int dlo = b*RANGE;
  int range = n - dlo; if (range > RANGE) range = RANGE; if (range < 0) range = 0;
  int cnt = bcur[b] - b*BCAP;
  for (int t=tid; t<RANGE; t+=256) hist[t] = 0;
  __syncthreads();
  const unsigned* sl = tmp + (size_t)b*BCAP;
  for (int j=tid; j<cnt; j+=256) atomicAdd(&hist[sl[j] & 2047u], 1);
  __syncthreads();
  int s = 0; int loc[K];
  #pragma unroll
  for (int kk=0; kk<K; ++kk){
    int idx = tid*K + kk;
    int v = (idx < RANGE) ? hist[idx] : 0;
    loc[kk] = s; s += v;
  }
  part[tid] = s; __syncthreads();
  int own = s;
  for (int st=1; st<256; st<<=1){
    int x = (tid >= st) ? part[tid-st] : 0;
    __syncthreads();
    part[tid] += x;
    __syncthreads();
  }
  int ebase = part[tid] - own;      // exclusive block base for this thread's chunk
  int gb = bb[b];
  __syncthreads();                  // all loc[] reads of hist done -> safe to overwrite
  #pragma unroll
  for (int kk=0; kk<K; ++kk){
    int idx = tid*K + kk;
    if (idx < RANGE){
      int ex = ebase + loc[kk];
      if (idx < range) offs[dlo+idx] = gb + ex;
      hist[idx] = ex;               // becomes running cursor
    }
  }
  __syncthreads();
  for (int j=tid; j<cnt; j+=256){
    unsigned p = sl[j];
    int pos = atomicAdd(&hist[p & 2047u], 1);
    csr[gb + pos] = (int)(p >> 11);
  }
}

// ============================ label CSR (small: targets L2-resident) ============================

__global__ __launch_bounds__(256) void k_count_lab(const int* __restrict__ labels, int n, int* __restrict__ cnt){
  int i = blockIdx.x*256 + threadIdx.x;
  if (i < n) atomicAdd(&cnt[labels[i]], 1);
}

__global__ __launch_bounds__(256) void k_chunk_sum(const int* __restrict__ cnt, int n, int* __restrict__ part){
  __shared__ int sd[256];
  int t = threadIdx.x, base = blockIdx.x*2048;
  int s = 0;
  #pragma unroll
  for (int r=0;r<8;++r){ int i = base + t*8 + r; if (i<n) s += cnt[i]; }
  sd[t]=s; __syncthreads();
  for (int st=128; st>0; st>>=1){ if (t<st) sd[t]+=sd[t+st]; __syncthreads(); }
  if (t==0) part[blockIdx.x]=sd[0];
}

__global__ void k_scan_part(int* part, int B, int* offs, int n){
  int lane = threadIdx.x & 63;
  int v = (lane < B) ? part[lane] : 0;
  int orig = v;
  #pragma unroll
  for (int st=1; st<64; st<<=1){
    int x = __shfl_up(v, st, 64);
    if (lane >= st) v += x;
  }
  if (lane < B) part[lane] = v - orig;
  if (lane == 63) offs[n] = v;
}

__global__ __launch_bounds__(256) void k_chunk_scan(const int* __restrict__ cnt, int n,
                                                    const int* __restrict__ part, int* __restrict__ offs){
  __shared__ int sd[256];
  int t=threadIdx.x, base=blockIdx.x*2048;
  int v[8]; int s=0;
  #pragma unroll
  for (int r=0;r<8;++r){ int i=base+t*8+r; v[r] = (i<n)?cnt[i]:0; s+=v[r]; }
  sd[t]=s; __syncthreads();
  for (int st=1; st<256; st<<=1){
    int x = (t>=st)? sd[t-st] : 0;
    __syncthreads();
    sd[t]+=x;
    __syncthreads();
  }
  int acc = part[blockIdx.x] + sd[t] - s;
  #pragma unroll
  for (int r=0;r<8;++r){ int i=base+t*8+r; if (i<n) offs[i]=acc; acc+=v[r]; }
}

__global__ __launch_bounds__(256) void k_fill_lab(const int* __restrict__ labels, int n,
                                                  const int* __restrict__ offs, int* __restrict__ cur,
                                                  int* __restrict__ csr){
  int i = blockIdx.x*256 + threadIdx.x;
  if (i < n){
    int d = labels[i];
    int p = atomicAdd(&cur[d], 1);
    csr[offs[d]+p] = i;
  }
}

// ============================ fused feature encoder: rel + f1 + g0(bf16) ============================

__global__ __launch_bounds__(256) void k_f1f(const float* __restrict__ features, const float* __restrict__ points,
                                             const float* __restrict__ centers, const int* __restrict__ labels,
                                             const float* __restrict__ W, const float* __restrict__ b,
                                             const float* __restrict__ EW, const float* __restrict__ Eb,
                                             float* __restrict__ rel, float* __restrict__ f1,
                                             ushortT* __restrict__ gout, int n){
  __shared__ float rowbuf[256];
  int tid = threadIdx.x, lane = tid & 63, wslot = tid >> 6;
  int gw = (blockIdx.x*256 + tid) >> 6;
  int nw = (gridDim.x*256) >> 6;
  float Wf0=W[0*64+lane], Wf1=W[1*64+lane], Wf2=W[2*64+lane], Wf3=W[3*64+lane];
  float wr0=W[4*64+lane], wr1=W[5*64+lane], wr2=W[6*64+lane];
  float bias=b[lane];
  float EWc[64];
  #pragma unroll
  for (int k=0;k<64;++k) EWc[k] = EW[k*64+lane];
  float eb = Eb[lane];
  for (int i=gw; i<n; i+=nw){
    int lb = labels[i];
    float rx = points[i*3+0]-centers[lb*3+0];
    float ry = points[i*3+1]-centers[lb*3+1];
    float rz = points[i*3+2]-centers[lb*3+2];
    if (lane==0){ rel[i*3+0]=rx; rel[i*3+1]=ry; rel[i*3+2]=rz; }
    float acc = bias + wr0*rx + wr1*ry + wr2*rz;
    acc += features[i*4+0]*Wf0 + features[i*4+1]*Wf1;
    acc += features[i*4+2]*Wf2 + features[i*4+3]*Wf3;
    acc = fmaxf(acc, 0.f);
    f1[(size_t)i*64+lane] = acc;
    rowbuf[wslot*64+lane] = acc;
    __builtin_amdgcn_wave_barrier();
    const float4* rb = (const float4*)(rowbuf + wslot*64);
    float e0=0.f,e1=0.f,e2=0.f,e3=0.f;
    #pragma unroll
    for (int kk=0; kk<16; ++kk){
      float4 a4 = rb[kk];
      e0 += a4.x*EWc[4*kk+0]; e1 += a4.y*EWc[4*kk+1];
      e2 += a4.z*EWc[4*kk+2]; e3 += a4.w*EWc[4*kk+3];
    }
    gout[(size_t)i*64+lane] = f2bf(eb + (e0+e1) + (e2+e3));
  }
}

// ============================ node MLP with fused emit ============================
// EMODE: 0=none, 1=emit g bf16 (64-wide EW + Eb), 2=emit h bf16 (67-wide EW: +rel rows, +Eb, relu),
//        3=emit out8 fp32 (EW=W_c 64x8, Eb=b_c)

template<bool RELU, bool USE_REL, int NRES, bool GATHER, bool WRITEOUT, int EMODE>
__global__ __launch_bounds__(256) void k_mlp(const float* __restrict__ A, const int* __restrict__ gidx,
                                             const float* __restrict__ rel,
                                             const float* __restrict__ W, const float* __restrict__ b,
                                             const float* __restrict__ r1, const float* __restrict__ r2,
                                             float* __restrict__ out,
                                             const float* __restrict__ EW, const float* __restrict__ Eb,
                                             void* __restrict__ eout, int n){
  __shared__ float rowbuf[256];
  __shared__ float wcs[512];
  int tid = threadIdx.x, lane = tid & 63, wslot = tid >> 6;
  if (EMODE == 3){
    wcs[tid] = EW[tid]; wcs[tid+256] = EW[tid+256];
    __syncthreads();
  }
  int gw = (blockIdx.x*256 + tid) >> 6;
  int nw = (gridDim.x*256) >> 6;
  float Wc[64];
  #pragma unroll
  for (int k=0;k<64;++k) Wc[k] = W[k*64+lane];
  float wr0=0.f, wr1=0.f, wr2=0.f;
  if (USE_REL){ wr0=W[64*64+lane]; wr1=W[65*64+lane]; wr2=W[66*64+lane]; }
  float bias = b[lane];
  float EWc[64];
  float er0=0.f, er1=0.f, er2=0.f, eb=0.f;
  if (EMODE==1 || EMODE==2){
    #pragma unroll
    for (int k=0;k<64;++k) EWc[k] = EW[k*64+lane];
    eb = Eb[lane];
  }
  if (EMODE==2){ er0=EW[64*64+lane]; er1=EW[65*64+lane]; er2=EW[66*64+lane]; }
  float ebias3 = 0.f;
  if (EMODE==3 && lane < 8) ebias3 = Eb[lane];
  for (int i=gw; i<n; i+=nw){
    int ar = GATHER ? gidx[i] : i;
    const float4* Arow = (const float4*)(A + (size_t)ar*64);
    float a0=0.f,a1=0.f,a2=0.f,a3=0.f;
    #pragma unroll
    for (int kk=0; kk<16; ++kk){
      float4 a4 = Arow[kk];
      a0 += a4.x*Wc[4*kk+0];
      a1 += a4.y*Wc[4*kk+1];
      a2 += a4.z*Wc[4*kk+2];
      a3 += a4.w*Wc[4*kk+3];
    }
    float acc = bias + (a0+a1) + (a2+a3);
    if (USE_REL) acc += rel[i*3+0]*wr0 + rel[i*3+1]*wr1 + rel[i*3+2]*wr2;
    if (RELU) acc = fmaxf(acc, 0.f);
    if (NRES>=1) acc += r1[(size_t)i*64+lane];
    if (NRES>=2) acc += r2[(size_t)i*64+lane];
    if (WRITEOUT) out[(size_t)i*64+lane] = acc;
    if (EMODE){
      rowbuf[wslot*64+lane] = acc;
      __builtin_amdgcn_wave_barrier();
      if (EMODE == 3){
        if (lane < 8){
          const float* rw = rowbuf + wslot*64;
          float s0=0.f, s1=0.f;
          #pragma unroll
          for (int k=0;k<64;k+=2){
            s0 += rw[k]  *wcs[k*8+lane];
            s1 += rw[k+1]*wcs[(k+1)*8+lane];
          }
          ((float*)eout)[(size_t)i*8+lane] = ebias3 + s0 + s1;
        }
      } else {
        const float4* rb = (const float4*)(rowbuf + wslot*64);
        float e0=0.f,e1=0.f,e2=0.f,e3=0.f;
        #pragma unroll
        for (int kk=0; kk<16; ++kk){
          float4 a4 = rb[kk];
          e0 += a4.x*EWc[4*kk+0]; e1 += a4.y*EWc[4*kk+1];
          e2 += a4.z*EWc[4*kk+2]; e3 += a4.w*EWc[4*kk+3];
        }
        float g = eb + (e0+e1) + (e2+e3);
        if (EMODE==2){
          g += rel[i*3+0]*er0 + rel[i*3+1]*er1 + rel[i*3+2]*er2;
          g = fmaxf(g, 0.f);
        }
        ((ushortT*)eout)[(size_t)i*64+lane] = f2bf(g);
      }
    }
  }
}

// ============================ edge aggregation (segment max via CSR) ============================

__global__ __launch_bounds__(256) void k_edge_agg(const int* __restrict__ offs, const int* __restrict__ csr,
                                                  const float* __restrict__ pos, const ushortT* __restrict__ g,
                                                  const float* __restrict__ Wp, float* __restrict__ agg, int n){
  int lane = threadIdx.x & 63;
  int gw = (blockIdx.x*256 + threadIdx.x) >> 6;
  int nw = (gridDim.x*256) >> 6;
  float w0 = Wp[0*64+lane], w1 = Wp[1*64+lane], w2 = Wp[2*64+lane];
  for (int i=gw; i<n; i+=nw){
    int b = offs[i], e = offs[i+1];
    float px = pos[i*3+0], py = pos[i*3+1], pz = pos[i*3+2];
    float m0=0.f, m1=0.f, m2=0.f, m3=0.f;
    int k = b;
    for (; k+4<=e; k+=4){
      int s0=csr[k+0], s1=csr[k+1], s2=csr[k+2], s3=csr[k+3];
      const float* p0=pos+3*s0; const float* p1=pos+3*s1;
      const float* p2=pos+3*s2; const float* p3=pos+3*s3;
      float g0=bf2f(g[(size_t)s0*64+lane]);
      float g1=bf2f(g[(size_t)s1*64+lane]);
      float g2=bf2f(g[(size_t)s2*64+lane]);
      float g3=bf2f(g[(size_t)s3*64+lane]);
      m0=fmaxf(m0, g0 + w0*(p0[0]-px) + w1*(p0[1]-py) + w2*(p0[2]-pz));
      m1=fmaxf(m1, g1 + w0*(p1[0]-px) + w1*(p1[1]-py) + w2*(p1[2]-pz));
      m2=fmaxf(m2, g2 + w0*(p2[0]-px) + w1*(p2[1]-py) + w2*(p2[2]-pz));
      m3=fmaxf(m3, g3 + w0*(p3[0]-px) + w1*(p3[1]-py) + w2*(p3[2]-pz));
    }
    for (; k<e; ++k){
      int s=csr[k];
      m0=fmaxf(m0, bf2f(g[(size_t)s*64+lane]) + w0*(pos[3*s]-px) + w1*(pos[3*s+1]-py) + w2*(pos[3*s+2]-pz));
    }
    agg[(size_t)i*64+lane] = fmaxf(fmaxf(m0,m1),fmaxf(m2,m3));
  }
}

// ============================ segment sum via label CSR (gather) ============================

__global__ __launch_bounds__(256) void k_seg_gather(const int* __restrict__ offs, const int* __restrict__ csr,
                                                    const ushortT* __restrict__ h, float* __restrict__ c, int m){
  int lane = threadIdx.x & 63;
  int wv = (blockIdx.x*256 + threadIdx.x) >> 6;
  if (wv >= m) return;
  int b = offs[wv], e = offs[wv+1];
  float acc = 0.f;
  for (int k=b; k<e; ++k){
    int i = csr[k];
    acc += bf2f(h[(size_t)i*64+lane]);
  }
  c[(size_t)wv*64+lane] = acc;
}

// ============================ host launcher ============================

extern "C" void kernel_launch(void* const* d_in, const int* in_sizes, int n_in,
                              void* d_out, int out_size, void* d_ws, size_t ws_size,
                              hipStream_t stream){
  const float* features = (const float*)d_in[0];
  const float* points   = (const float*)d_in[1];
  const float* centers  = (const float*)d_in[2];
  const int*   l0e      = (const int*)d_in[3];
  const int*   l1e      = (const int*)d_in[4];
  const int*   labels   = (const int*)d_in[5];
  const float* W_fe = (const float*)d_in[6];
  const float* b_fe = (const float*)d_in[7];
  const float* mWe  = (const float*)d_in[8];   // (4,67,64)
  const float* mbe  = (const float*)d_in[9];
  const float* mWu  = (const float*)d_in[10];  // (4,64,64)
  const float* mbu  = (const float*)d_in[11];
  const float* W_m1 = (const float*)d_in[12];
  const float* b_m1 = (const float*)d_in[13];
  const float* W_m2 = (const float*)d_in[14];
  const float* b_m2 = (const float*)d_in[15];
  const float* gWe  = (const float*)d_in[16];  // (2,67,64)
  const float* gbe  = (const float*)d_in[17];
  const float* gWu  = (const float*)d_in[18];
  const float* gbu  = (const float*)d_in[19];
  const float* W_l  = (const float*)d_in[20];
  const float* b_l  = (const float*)d_in[21];
  const float* W_c  = (const float*)d_in[22];
  const float* b_c  = (const float*)d_in[23];
  float* out = (float*)d_out;

  char* w = (char*)d_ws;
  size_t off = 0;
  auto alloc = [&](size_t bytes)->void*{
    void* p = (void*)(w + off);
    off = (off + bytes + 255) & ~(size_t)255;
    return p;
  };
  float* rel  = (float*)alloc((size_t)N_PTS*3*4);
  float* buf0 = (float*)alloc((size_t)N_PTS*64*4);     // f1 -> f5
  float* buf1 = (float*)alloc((size_t)N_PTS*64*4);     // f2
  float* buf2 = (float*)alloc((size_t)N_PTS*64*4);     // f2_1
  float* buf3 = (float*)alloc((size_t)N_PTS*64*4);     // f6
  ushortT* gbuf = (ushortT*)alloc((size_t)N_PTS*64*2); // g / h (bf16)
  float* abuf = (float*)alloc((size_t)N_PTS*64*4);     // agg
  float* cbuf = (float*)alloc((size_t)M_CL*64*4);
  float* f3   = (float*)alloc((size_t)M_CL*64*4);
  ushortT* cg = (ushortT*)alloc((size_t)M_CL*64*2);
  float* cagg = (float*)alloc((size_t)M_CL*64*4);
  float* f4   = (float*)alloc((size_t)M_CL*64*4);
  float* f41  = (float*)alloc((size_t)M_CL*64*4);
  int* offs0 = (int*)alloc((size_t)(N_PTS+1)*4);
  int* csr0  = (int*)alloc((size_t)E0_N*4);
  int* offs1 = (int*)alloc((size_t)(M_CL+1)*4);
  int* csr1  = (int*)alloc((size_t)E1_N*4);
  unsigned* tmp0 = (unsigned*)alloc((size_t)NB*BCAP0*4);  // 8.4 MB
  unsigned* tmp1 = (unsigned*)alloc((size_t)NB*BCAP1*4);  // 2.1 MB
  int* bcur0 = (int*)alloc(NB*4);
  int* bcur1 = (int*)alloc(NB*4);
  int* bb0   = (int*)alloc(NB*4);
  int* bb1   = (int*)alloc(NB*4);
  // label CSR (zeroed block)
  char* zbase = (char*)alloc(0);
  int* cntL = (int*)alloc((size_t)M_CL*4);
  int* curL = (int*)alloc((size_t)M_CL*4);
  size_t zbytes = (size_t)((char*)(w+off) - zbase);
  int* offsL = (int*)alloc((size_t)(M_CL+1)*4);
  int* csrL  = (int*)alloc((size_t)N_PTS*4);
  int* partL = (int*)alloc(64*4);
  (void)ws_size; (void)in_sizes; (void)n_in; (void)out_size;

  const int GB_N = 2048;
  const int GB_M = 512;

  hipMemsetAsync(zbase, 0, zbytes, stream);

  // ---- CSR builds (bucketed counting sort) ----
  k_binit<<<1, 256, 0, stream>>>(bcur0, bcur1);
  k_bin<RANGE0><<<256, 256, 0, stream>>>(l0e, E0_N, bcur0, tmp0);
  k_bin<RANGE1><<<196, 256, 0, stream>>>(l1e, E1_N, bcur1, tmp1);
  k_scan_bases<<<2, 64, 0, stream>>>(bcur0, bb0, offs0+N_PTS, bcur1, bb1, offs1+M_CL);
  k_csr_build<RANGE0,BCAP0><<<NB, 256, 0, stream>>>(tmp0, bcur0, bb0, N_PTS, offs0, csr0);
  k_csr_build<RANGE1,BCAP1><<<NB, 256, 0, stream>>>(tmp1, bcur1, bb1, M_CL, offs1, csr1);

  // ---- label CSR ----
  k_count_lab<<<(N_PTS+255)/256, 256, 0, stream>>>(labels, N_PTS, cntL);
  k_chunk_sum<<<7, 256, 0, stream>>>(cntL, M_CL, partL);
  k_scan_part<<<1, 64, 0, stream>>>(partL, 7, offsL, M_CL);
  k_chunk_scan<<<7, 256, 0, stream>>>(cntL, M_CL, partL, offsL);
  k_fill_lab<<<(N_PTS+255)/256, 256, 0, stream>>>(labels, N_PTS, offsL, curL, csrL);

  // ---- encoder: rel + f1 + g0 ----
  k_f1f<<<GB_N, 256, 0, stream>>>(features, points, centers, labels, W_fe, b_fe,
                                  mWe+192, mbe, rel, buf0, gbuf, N_PTS);

  // ---- mini layer 0: f2 + g1 ----
  k_edge_agg<<<GB_N,256,0,stream>>>(offs0, csr0, points, gbuf, mWe+0*4288, abuf, N_PTS);
  k_mlp<true,false,1,false,true,1><<<GB_N,256,0,stream>>>(abuf, nullptr, nullptr, mWu+0*4096, mbu+0*64,
      buf0, nullptr, buf1, mWe+1*4288+192, mbe+64, gbuf, N_PTS);

  // ---- mini layer 1: f2_1 + h (bf16 into gbuf) ----
  k_edge_agg<<<GB_N,256,0,stream>>>(offs0, csr0, points, gbuf, mWe+1*4288, abuf, N_PTS);
  k_mlp<true,false,1,false,true,2><<<GB_N,256,0,stream>>>(abuf, nullptr, rel, mWu+1*4096, mbu+1*64,
      buf1, nullptr, buf2, W_m1, b_m1, gbuf, N_PTS);

  // ---- c = segment_sum(h) ; f3 + cg0 ----
  k_seg_gather<<<(M_CL*64+255)/256, 256, 0, stream>>>(offsL, csrL, gbuf, cbuf, M_CL);
  k_mlp<true,false,0,false,true,1><<<GB_M,256,0,stream>>>(cbuf, nullptr, nullptr, W_m2, b_m2,
      nullptr, nullptr, f3, gWe+0*4288+192, gbe+0*64, cg, M_CL);

  // ---- cluster layer 0: f4 + cg1 ----
  k_edge_agg<<<GB_M,256,0,stream>>>(offs1, csr1, centers, cg, gWe+0*4288, cagg, M_CL);
  k_mlp<true,false,1,false,true,1><<<GB_M,256,0,stream>>>(cagg, nullptr, nullptr, gWu+0*4096, gbu+0*64,
      f3, nullptr, f4, gWe+1*4288+192, gbe+64, cg, M_CL);

  // ---- cluster layer 1: f4_1 ----
  k_edge_agg<<<GB_M,256,0,stream>>>(offs1, csr1, centers, cg, gWe+1*4288, cagg, M_CL);
  k_mlp<true,false,1,false,true,0><<<GB_M,256,0,stream>>>(cagg, nullptr, nullptr, gWu+1*4096, gbu+1*64,
      f4, nullptr, f41, nullptr, nullptr, nullptr, M_CL);

  // ---- f5 = relu([f4_1[labels], rel] @ W_l + b_l) + g2 ----
  k_mlp<true,true,0,true,true,1><<<GB_N,256,0,stream>>>(f41, labels, rel, W_l, b_l,
      nullptr, nullptr, buf0, mWe+2*4288+192, mbe+128, gbuf, N_PTS);

  // ---- mini layer 2: f6 = relu(agg@Wu2+bu2) + f5 + f2_1 ; g3 ----
  k_edge_agg<<<GB_N,256,0,stream>>>(offs0, csr0, points, gbuf, mWe+2*4288, abuf, N_PTS);
  k_mlp<true,false,2,false,true,1><<<GB_N,256,0,stream>>>(abuf, nullptr, nullptr, mWu+2*4096, mbu+2*64,
      buf0, buf2, buf3, mWe+3*4288+192, mbe+192, gbuf, N_PTS);

  // ---- mini layer 3 + classifier: out = (relu(agg@Wu3+bu3)+f6+f2) @ W_c + b_c ----
  k_edge_agg<<<GB_N,256,0,stream>>>(offs0, csr0, points, gbuf, mWe+3*4288, abuf, N_PTS);
  k_mlp<true,false,2,false,false,3><<<GB_N,256,0,stream>>>(abuf, nullptr, nullptr, mWu+3*4096, mbu+3*64,
      buf3, buf1, nullptr, W_c, b_c, out, N_PTS);
}